// Round 1
// baseline (1295.421 us; speedup 1.0000x reference)
//
#include <hip/hip_runtime.h>
#include <hip/hip_bf16.h>

// QLSTM: T=512, B=256, D=128, H=256.  z = [x,h] @ W^T + b, W=[4H,384]
// Round 9: latency-bound chained exchange -> shrink the chain and the
// critical path.
//  - Grid 128 blocks x 512 threads. Block (bg, jg): bg = blockIdx&15 (16
//    batch rows), jg = blockIdx>>4 (32 H columns). W_s tile 128x384 bf16
//    (98 KB LDS), 8 waves each computing one 16x16 MFMA output tile.
//  - Chain = blocks with equal (blockIdx & 15): 8 members (was 16) -> half
//    the poll congestion per XCD, half the straggler width. Still XCD-local
//    under round-robin dispatch (stride 16 == 0 mod 8).
//  - K-split: x-part (K=0..127) MFMA precomputed right after the h store
//    (hidden under other blocks' latency); only h-part (K=128..383) sits
//    between poll-hit and store.
//  - s_sleep(1) backoff between failed fast polls (first try immediate).
//  - Exchange mechanism unchanged (proven): tagged h-words, dual plane
//    (fast plain / slow sc1), fused-asm poll, bounded fast tries then sc1
//    fallback that always succeeds.

#define T_STEPS 512
#define BATCH   256
#define DIN     128
#define HID     256
#define KDIM    384
#define LDK     392   // padded LDS row stride (shorts)
#define GRIDN   128
#define BLOCKT  512
#define NPOLL   96    // bounded fast-poll tries before sc1 fallback

typedef __attribute__((ext_vector_type(8))) short short8;
typedef __attribute__((ext_vector_type(4))) short short4v;
typedef __attribute__((ext_vector_type(4))) float f32x4;

__device__ __forceinline__ unsigned short f2bf(float f) {
    unsigned u = __float_as_uint(f);
    unsigned r = (u + 0x7FFFu + ((u >> 16) & 1u)) >> 16;
    return (unsigned short)r;
}
__device__ __forceinline__ float bf2f(unsigned short s) {
    return __uint_as_float(((unsigned)s) << 16);
}
__device__ __forceinline__ float sigmoid_f(float x) {
    return 1.f / (1.f + __expf(-x));
}
__device__ __forceinline__ float tanh_f(float x) {
    float e = __expf(2.f * x);
    return 1.f - 2.f / (e + 1.f);
}
// ---- fused poll loads: 2 x dwordx4 + waitcnt in ONE asm block ----
__device__ __forceinline__ void poll_load2_sc0(const unsigned int* p, uint4& a,
                                               uint4& b) {
    asm volatile(
        "global_load_dwordx4 %0, %2, off sc0\n\t"
        "global_load_dwordx4 %1, %2, off offset:16 sc0\n\t"
        "s_waitcnt vmcnt(0)"
        : "=&v"(a), "=&v"(b) : "v"(p) : "memory");
}
__device__ __forceinline__ void poll_load2_sc1(const unsigned int* p, uint4& a,
                                               uint4& b) {
    asm volatile(
        "global_load_dwordx4 %0, %2, off sc1\n\t"
        "global_load_dwordx4 %1, %2, off offset:16 sc1\n\t"
        "s_waitcnt vmcnt(0)"
        : "=&v"(a), "=&v"(b) : "v"(p) : "memory");
}
__device__ __forceinline__ void store_plain_u32(unsigned int* p, unsigned int v) {
    asm volatile("global_store_dword %0, %1, off" :: "v"(p), "v"(v) : "memory");
}
__device__ __forceinline__ void store_sc1_u32(unsigned int* p, unsigned int v) {
    asm volatile("global_store_dword %0, %1, off sc1" :: "v"(p), "v"(v) : "memory");
}
__device__ __forceinline__ unsigned pack2bf(unsigned lo, unsigned hi) {
    return (hi & 0xFFFF0000u) | (lo >> 16);
}
__device__ __forceinline__ bool tags_ok2(const uint4& a, const uint4& b,
                                         unsigned tag) {
    return ((a.x ^ tag) & 0xFFFFu) == 0 && ((a.y ^ tag) & 0xFFFFu) == 0 &&
           ((a.z ^ tag) & 0xFFFFu) == 0 && ((a.w ^ tag) & 0xFFFFu) == 0 &&
           ((b.x ^ tag) & 0xFFFFu) == 0 && ((b.y ^ tag) & 0xFFFFu) == 0 &&
           ((b.z ^ tag) & 0xFFFFu) == 0 && ((b.w ^ tag) & 0xFFFFu) == 0;
}

// ---- pack weights: Wpack[n][k] bf16, n = g*256 + j, row-major [1024][384] ----
__global__ __launch_bounds__(256) void pack_w(
    const float* __restrict__ Wf, const float* __restrict__ Wi,
    const float* __restrict__ Wg, const float* __restrict__ Wo,
    unsigned short* __restrict__ Wp) {
    int idx = blockIdx.x * 256 + threadIdx.x;
    int n = idx / KDIM;
    int k = idx - n * KDIM;
    int g = n >> 8, j = n & 255;
    const float* s = (g == 0) ? Wf : (g == 1) ? Wi : (g == 2) ? Wg : Wo;
    Wp[idx] = f2bf(s[j * KDIM + k]);
}

__global__ __launch_bounds__(256) void pack_b(
    const float* __restrict__ bf, const float* __restrict__ bi,
    const float* __restrict__ bg, const float* __restrict__ bo,
    float* __restrict__ bp) {
    int n = blockIdx.x * 256 + threadIdx.x;
    int g = n >> 8, j = n & 255;
    const float* s = (g == 0) ? bf : (g == 1) ? bi : (g == 2) ? bg : bo;
    bp[n] = s[j];
}

// ---- zero all 4 exchange planes: fast[2] + slow[2] (h_0 = 0, tag 0) ----
__global__ __launch_bounds__(256) void init_k(unsigned int* __restrict__ hxp) {
    int tid = blockIdx.x * 256 + threadIdx.x;   // grid 256 -> 65536
    hxp[tid] = 0u;
    hxp[65536 + tid] = 0u;
    hxp[131072 + tid] = 0u;
    hxp[196608 + tid] = 0u;
}

// ---- persistent LSTM: all 512 steps in one launch ----
__global__ __launch_bounds__(BLOCKT, 1) void lstm_persist(
    const float* __restrict__ X,            // [T,B,D] fp32
    const unsigned short* __restrict__ W,   // [1024][384] bf16
    const float* __restrict__ bias,         // [1024]
    unsigned int* __restrict__ hxp,         // fast[2][B][H] + slow[2][B][H]
    unsigned short* __restrict__ hist,      // [T][B][H] bf16
    float* __restrict__ out) {
    __shared__ __align__(16) unsigned short W_s[128 * LDK];   // 100352 B
    __shared__ __align__(16) unsigned short comb_s[16 * LDK]; // 12544 B
    __shared__ __align__(16) float z_s[8 * 272];              // 8704 B
    __shared__ int fastok_s;

    const int tid = threadIdx.x;            // 0..511
    // chain = same (blockIdx & 15): stride-16 members are XCD-local under
    // round-robin dispatch (16 % 8 == 0)
    const int bg = blockIdx.x & 15, jg = blockIdx.x >> 4;   // jg 0..7
    const int b0 = bg * 16, j0 = jg * 32;
    const int wave = tid >> 6, lane = tid & 63;             // wave 0..7
    const int l16 = lane & 15, quad = lane >> 4;
    const int bi = tid >> 5, jj = tid & 31;                 // owns (b0+bi, j0+jj)
    const int b = b0 + bi, j = j0 + jj;

    // stage W tile once: local row = g*32+jc <- global row g*256+j0+jc ; 128x384
#pragma unroll
    for (int c = 0; c < 12; ++c) {
        int q = c * 512 + tid;
        int row = q / 48, c8 = q - row * 48;
        int g = row >> 5, jr = row & 31;
        short8 v = *(const short8*)(W + ((g * 256 + j0 + jr) * KDIM + c8 * 8));
        *(short8*)(&W_s[row * LDK + c8 * 8]) = v;
    }
    const float bs0 = bias[0 * HID + j];
    const float bs1 = bias[1 * HID + j];
    const float bs2 = bias[2 * HID + j];
    const float bs3 = bias[3 * HID + j];
    if (tid == 0) fastok_s = 1;

    float c_reg = 0.f;
    float h_final = 0.f;

    // MFMA fragment pointers (proven layout): A rows = batch (comb), B rows =
    // wave's 16 W_s rows; wave w covers W rows w*16..w*16+15 = (g = w>>1,
    // jc = (w&1)*16 + l16)
    const unsigned short* arow = &comb_s[l16 * LDK + quad * 8];
    const unsigned short* brow = &W_s[(wave * 16 + l16) * LDK + quad * 8];

    // ---- prologue: stage x_0, prefetch x_1, precompute x-part acc ----
    float4 xv = *(const float4*)(X + b * DIN + jj * 4);
    {
        short4v r;
        r.x = (short)f2bf(xv.x); r.y = (short)f2bf(xv.y);
        r.z = (short)f2bf(xv.z); r.w = (short)f2bf(xv.w);
        *(short4v*)(&comb_s[bi * LDK + jj * 4]) = r;
    }
    xv = *(const float4*)(X + (size_t)1 * BATCH * DIN + b * DIN + jj * 4);
    __syncthreads();

    f32x4 acc_x0 = {0.f, 0.f, 0.f, 0.f}, acc_x1 = {0.f, 0.f, 0.f, 0.f};
#pragma unroll
    for (int kt = 0; kt < 2; ++kt) {
        short8 a0 = *(const short8*)(arow + (2 * kt) * 32);
        short8 b0v = *(const short8*)(brow + (2 * kt) * 32);
        short8 a1 = *(const short8*)(arow + (2 * kt + 1) * 32);
        short8 b1v = *(const short8*)(brow + (2 * kt + 1) * 32);
        acc_x0 = __builtin_amdgcn_mfma_f32_16x16x32_bf16(a0, b0v, acc_x0, 0, 0, 0);
        acc_x1 = __builtin_amdgcn_mfma_f32_16x16x32_bf16(a1, b1v, acc_x1, 0, 0, 0);
    }

    for (int k = 0; k < T_STEPS; ++k) {
        const unsigned tag = (unsigned)k;
        // thread reads 8 h-words: row b0+bi, cols jj*8..jj*8+7 (one producer)
        const unsigned int* fb =
            hxp + (k & 1) * 65536 + (b0 + bi) * HID + jj * 8;
        const unsigned int* sb = fb + 131072;    // slow plane
        uint4 a, bq;
        const int usefast = fastok_s;            // racy read is fine (hint only)

        // ---- poll h_k: fast (bounded, backoff) then slow (guaranteed) ----
        if (usefast) {
            int tries = NPOLL;
            bool ok = false;
            for (;;) {
                poll_load2_sc0(fb, a, bq);
                if (tags_ok2(a, bq, tag)) { ok = true; break; }
                if (--tries == 0) break;
                __builtin_amdgcn_s_sleep(1);     // throttle spin traffic
            }
            if (!ok) {                       // bounded fallback: ALWAYS succeeds
                fastok_s = 0;
                for (;;) {
                    poll_load2_sc1(sb, a, bq);
                    if (tags_ok2(a, bq, tag)) break;
                    __builtin_amdgcn_s_sleep(1);
                }
            }
        } else {
            for (;;) {
                poll_load2_sc1(sb, a, bq);
                if (tags_ok2(a, bq, tag)) break;
                __builtin_amdgcn_s_sleep(1);
            }
        }

        // extract 8 bf16 -> comb_s[bi][DIN + jj*8]
        {
            uint4 p0;
            p0.x = pack2bf(a.x, a.y);   p0.y = pack2bf(a.z, a.w);
            p0.z = pack2bf(bq.x, bq.y); p0.w = pack2bf(bq.z, bq.w);
            *(uint4*)(&comb_s[bi * LDK + DIN + jj * 8]) = p0;
        }
        __syncthreads();   // barrier 1: h staged -> h-part MFMA

        // ---- h-part MFMA (K = 128..383), seeded with precomputed x-part ----
        f32x4 acc0 = acc_x0, acc1 = acc_x1;
#pragma unroll
        for (int kt = 2; kt < 6; ++kt) {
            short8 a0 = *(const short8*)(arow + (2 * kt) * 32);
            short8 b0v = *(const short8*)(brow + (2 * kt) * 32);
            short8 a1 = *(const short8*)(arow + (2 * kt + 1) * 32);
            short8 b1v = *(const short8*)(brow + (2 * kt + 1) * 32);
            acc0 = __builtin_amdgcn_mfma_f32_16x16x32_bf16(a0, b0v, acc0, 0, 0, 0);
            acc1 = __builtin_amdgcn_mfma_f32_16x16x32_bf16(a1, b1v, acc1, 0, 0, 0);
        }
#pragma unroll
        for (int r = 0; r < 4; ++r)
            z_s[wave * 272 + (quad * 4 + r) * 17 + l16] = acc0[r] + acc1[r];
        __syncthreads();   // barrier 2: z staged -> gates

        // ---- gates; dual-store h FIRST (chain-critical), rest after ----
        // z for (g, jc=jj): wave = g*2 + (jj>>4), col = jj&15, row = bi
        const int zc = bi * 17 + (jj & 15);
        const int zw = (jj >> 4) * 272;
        float zf = z_s[zw + 0 * 544 + zc] + bs0;
        float zi = z_s[zw + 1 * 544 + zc] + bs1;
        float zg = z_s[zw + 2 * 544 + zc] + bs2;
        float zo = z_s[zw + 3 * 544 + zc] + bs3;
        float fg = sigmoid_f(zf);
        float ig = sigmoid_f(zi);
        float gg = tanh_f(zg);
        float og = sigmoid_f(zo);
        c_reg = fg * c_reg + ig * gg;
        float hval = og * tanh_f(c_reg);
        unsigned short hb = f2bf(hval);
        unsigned int hword = ((unsigned)hb << 16) | (unsigned)(k + 1);
        unsigned int* fdst = hxp + ((k + 1) & 1) * 65536 + b * HID + j;
        store_plain_u32(fdst, hword);             // fast plane (producer's L2)
        store_sc1_u32(fdst + 131072, hword);      // slow plane (proven path)
        hist[(size_t)k * BATCH * HID + b * HID + j] = hb;

        // ---- off-critical-path tail: stage x_{k+1}, prefetch x_{k+2} ----
        if (k + 1 < T_STEPS) {
            short4v r;
            r.x = (short)f2bf(xv.x); r.y = (short)f2bf(xv.y);
            r.z = (short)f2bf(xv.z); r.w = (short)f2bf(xv.w);
            *(short4v*)(&comb_s[bi * LDK + jj * 4]) = r;
            if (k + 2 < T_STEPS) {
                xv = *(const float4*)(X + (size_t)(k + 2) * BATCH * DIN +
                                      b * DIN + jj * 4);
            }
        } else {
            h_final = hval;
        }
        __syncthreads();   // barrier 3: x staged -> x-part MFMA (hidden)

        if (k + 1 < T_STEPS) {
            f32x4 ax0 = {0.f, 0.f, 0.f, 0.f}, ax1 = {0.f, 0.f, 0.f, 0.f};
#pragma unroll
            for (int kt = 0; kt < 2; ++kt) {
                short8 a0 = *(const short8*)(arow + (2 * kt) * 32);
                short8 b0v = *(const short8*)(brow + (2 * kt) * 32);
                short8 a1 = *(const short8*)(arow + (2 * kt + 1) * 32);
                short8 b1v = *(const short8*)(brow + (2 * kt + 1) * 32);
                ax0 = __builtin_amdgcn_mfma_f32_16x16x32_bf16(a0, b0v, ax0, 0, 0, 0);
                ax1 = __builtin_amdgcn_mfma_f32_16x16x32_bf16(a1, b1v, ax1, 0, 0, 0);
            }
            acc_x0 = ax0; acc_x1 = ax1;
        }
    }

    // epilogue: hx (fp32) and cx outputs
    out[T_STEPS * BATCH * 2 + b * HID + j] = h_final;
    out[T_STEPS * BATCH * 2 + BATCH * HID + b * HID + j] = c_reg;
}

// ---- classifier head: one wave per (t,b) row ----
__global__ __launch_bounds__(256) void probs_k(
    const unsigned short* __restrict__ hist, const float* __restrict__ Wc,
    const float* __restrict__ bc, float* __restrict__ out) {
    const int wave = threadIdx.x >> 6, lane = threadIdx.x & 63;
    const size_t row = (size_t)blockIdx.x * 4 + wave;   // row = t*256+b < 131072
    const unsigned short* h = hist + row * HID;
    short4v hv = *(const short4v*)(h + lane * 4);
    const float4 wv = *(const float4*)(Wc + lane * 4);
    float p = bf2f((unsigned short)hv.x) * wv.x + bf2f((unsigned short)hv.y) * wv.y +
              bf2f((unsigned short)hv.z) * wv.z + bf2f((unsigned short)hv.w) * wv.w;
#pragma unroll
    for (int off = 32; off >= 1; off >>= 1) p += __shfl_down(p, off);
    if (lane == 0) {
        float prob = 1.f / (1.f + __expf(-(p + bc[0])));
        out[row * 2]     = prob;
        out[row * 2 + 1] = 1.f - prob;
    }
}

extern "C" void kernel_launch(void* const* d_in, const int* in_sizes, int n_in,
                              void* d_out, int out_size, void* d_ws, size_t ws_size,
                              hipStream_t stream) {
    const float* X  = (const float*)d_in[0];
    const float* Wf = (const float*)d_in[1];
    const float* bfp= (const float*)d_in[2];
    const float* Wi = (const float*)d_in[3];
    const float* bip= (const float*)d_in[4];
    const float* Wg = (const float*)d_in[5];
    const float* bgp= (const float*)d_in[6];
    const float* Wo = (const float*)d_in[7];
    const float* bop= (const float*)d_in[8];
    const float* Wc = (const float*)d_in[9];
    const float* bc = (const float*)d_in[10];
    float* out = (float*)d_out;

    char* ws = (char*)d_ws;
    unsigned short* Wpack = (unsigned short*)(ws);               // 786432 B
    float* bias = (float*)(ws + 786432);                         // 4096 B
    unsigned int* hxp = (unsigned int*)(ws + 790528);            // 1048576 B
    unsigned short* hist = (unsigned short*)(ws + 1839104);      // 67108864 B

    pack_w<<<1536, 256, 0, stream>>>(Wf, Wi, Wg, Wo, Wpack);
    pack_b<<<4, 256, 0, stream>>>(bfp, bip, bgp, bop, bias);
    init_k<<<256, 256, 0, stream>>>(hxp);

    void* kargs[6] = {(void*)&X, (void*)&Wpack, (void*)&bias,
                      (void*)&hxp, (void*)&hist, (void*)&out};
    (void)hipLaunchCooperativeKernel((const void*)lstm_persist, dim3(GRIDN),
                                     dim3(BLOCKT), kargs, 0, stream);

    probs_k<<<32768, 256, 0, stream>>>(hist, Wc, bc, out);
}